// Round 1
// baseline (15002.258 us; speedup 1.0000x reference)
//
#include <hip/hip_runtime.h>
#include <hip/hip_cooperative_groups.h>
#include <math.h>

namespace cg = cooperative_groups;

#define B_  32
#define S_  64
#define T_  64
#define P_  768
#define E_  512
#define H2_ 256
#define G2_ 1024
#define HD_ 512
#define V_  32000

__device__ __forceinline__ float sigf(float x) {
    return 1.0f / (1.0f + __expf(-x));
}
__device__ __forceinline__ float tanh_fast(float x) {
    // tanh(x) = 1 - 2/(exp(2x)+1); exact limits at +-inf
    return 1.0f - 2.0f / (__expf(2.0f * x) + 1.0f);
}

// ---------------------------------------------------------------------------
// prep: transpose Whh_f/Whh_b to [k][gate]; tokens
// ---------------------------------------------------------------------------
__global__ void k_prep(const int* __restrict__ ys,
                       const float* __restrict__ Whh_f, const float* __restrict__ Whh_b,
                       float* __restrict__ WhhT_f, float* __restrict__ WhhT_b,
                       int* __restrict__ tokens)
{
    int i = blockIdx.x * blockDim.x + threadIdx.x;
    int n = gridDim.x * blockDim.x;
    for (int idx = i; idx < G2_ * H2_; idx += n) {
        int k = idx / G2_, g = idx % G2_;
        WhhT_f[idx] = Whh_f[g * H2_ + k];
        WhhT_b[idx] = Whh_b[g * H2_ + k];
    }
    for (int idx = i; idx < T_ * B_; idx += n) {
        int t = idx / B_, b = idx % B_;
        tokens[idx] = (t == 0) ? 1 : ys[b * (T_ + 1) + t];
    }
}

// ---------------------------------------------------------------------------
// Tiled fp32 GEMM:  C[m,n] = bias[n] + sum_k A(m)[k] * W[n*ldw + woff + k]
// A(m) = gidx ? A + gidx[m]*lda : A + m*lda.  M%64==0, N%64==0, K%16==0.
// ---------------------------------------------------------------------------
__global__ __launch_bounds__(256)
void gemm_f32(const float* __restrict__ A, const int* __restrict__ gidx, int lda,
              const float* __restrict__ W, int ldw, int woff,
              const float* __restrict__ bias,
              float* __restrict__ C, int ldc, int K)
{
    __shared__ __align__(16) float As[16][64];
    __shared__ __align__(16) float Bs[16][64];
    const int m0 = blockIdx.y * 64;
    const int n0 = blockIdx.x * 64;
    const int tid = threadIdx.x;
    const int tm = tid & 15, tn = tid >> 4;
    const int la_m = tid >> 2;        // 0..63
    const int la_k = (tid & 3) * 4;   // 0,4,8,12
    float acc[4][4] = {};

    const int am = m0 + la_m;
    const float* arow = A + (long)(gidx ? gidx[am] : am) * lda;
    const float* wrow = W + (long)(n0 + la_m) * ldw + woff;

    for (int k0 = 0; k0 < K; k0 += 16) {
        float4 av = *(const float4*)(arow + k0 + la_k);
        float4 wv = *(const float4*)(wrow + k0 + la_k);
        As[la_k + 0][la_m] = av.x; As[la_k + 1][la_m] = av.y;
        As[la_k + 2][la_m] = av.z; As[la_k + 3][la_m] = av.w;
        Bs[la_k + 0][la_m] = wv.x; Bs[la_k + 1][la_m] = wv.y;
        Bs[la_k + 2][la_m] = wv.z; Bs[la_k + 3][la_m] = wv.w;
        __syncthreads();
        #pragma unroll
        for (int kk = 0; kk < 16; kk++) {
            float4 a = *(const float4*)&As[kk][tm * 4];
            float4 b = *(const float4*)&Bs[kk][tn * 4];
            acc[0][0] += a.x * b.x; acc[0][1] += a.x * b.y; acc[0][2] += a.x * b.z; acc[0][3] += a.x * b.w;
            acc[1][0] += a.y * b.x; acc[1][1] += a.y * b.y; acc[1][2] += a.y * b.z; acc[1][3] += a.y * b.w;
            acc[2][0] += a.z * b.x; acc[2][1] += a.z * b.y; acc[2][2] += a.z * b.z; acc[2][3] += a.z * b.w;
            acc[3][0] += a.w * b.x; acc[3][1] += a.w * b.y; acc[3][2] += a.w * b.z; acc[3][3] += a.w * b.w;
        }
        __syncthreads();
    }
    float b0 = bias ? bias[n0 + tn * 4 + 0] : 0.f;
    float b1 = bias ? bias[n0 + tn * 4 + 1] : 0.f;
    float b2 = bias ? bias[n0 + tn * 4 + 2] : 0.f;
    float b3 = bias ? bias[n0 + tn * 4 + 3] : 0.f;
    #pragma unroll
    for (int i = 0; i < 4; i++) {
        long m = m0 + tm * 4 + i;
        float4 o = make_float4(acc[i][0] + b0, acc[i][1] + b1, acc[i][2] + b2, acc[i][3] + b3);
        *(float4*)&C[m * ldc + n0 + tn * 4] = o;
    }
}

// ---------------------------------------------------------------------------
// BiLSTM encoder recurrence: one WG per (b, dir); 1024 threads (one per gate).
// ---------------------------------------------------------------------------
__global__ __launch_bounds__(1024)
void k_encoder(const float* __restrict__ gpre_f, const float* __restrict__ gpre_b,
               const float* __restrict__ WhhT_f, const float* __restrict__ WhhT_b,
               const int* __restrict__ x_lens,
               float* __restrict__ enc, float* __restrict__ hid, float* __restrict__ xh0)
{
    const int b   = blockIdx.x >> 1;
    const int dir = blockIdx.x & 1;
    const float* gpre = dir ? gpre_b : gpre_f;
    const float* WT   = dir ? WhhT_b : WhhT_f;
    const int len = x_lens[b];
    __shared__ float h_lds[H2_];
    __shared__ float g_lds[G2_];
    const int tid = threadIdx.x;
    float c = 0.f;
    if (tid < H2_) h_lds[tid] = 0.f;
    __syncthreads();

    for (int t = 0; t < S_; t++) {
        bool valid = t < len;
        if (valid) {
            int s_in = dir ? (len - 1 - t) : t;
            float acc = gpre[(long)(b * S_ + s_in) * G2_ + tid];
            #pragma unroll 8
            for (int k = 0; k < H2_; k++)
                acc += h_lds[k] * WT[k * G2_ + tid];
            g_lds[tid] = acc;
            __syncthreads();
            if (tid < H2_) {
                float gi = g_lds[tid], gf = g_lds[H2_ + tid];
                float gg = g_lds[2 * H2_ + tid], go = g_lds[3 * H2_ + tid];
                c = sigf(gf) * c + sigf(gi) * tanh_fast(gg);
                float hn = sigf(go) * tanh_fast(c);
                h_lds[tid] = hn;
                enc[(long)(b * S_ + s_in) * E_ + dir * H2_ + tid] = hn;
            }
            __syncthreads();
        } else {
            if (tid < H2_)
                enc[(long)(b * S_ + t) * E_ + dir * H2_ + tid] = 0.f;
        }
    }
    if (tid < H2_) {
        hid[b * 1024 + dir * H2_ + tid]       = h_lds[tid]; // h
        hid[b * 1024 + 512 + dir * H2_ + tid] = c;          // c
        xh0[b * 1024 + 512 + dir * H2_ + tid] = h_lds[tid]; // h for gates step 0
    }
}

// ---------------------------------------------------------------------------
// Fused persistent decoder: all T=64 steps in one cooperative kernel.
// Grid = 256 WGs x 256 threads (1 WG/CU guaranteed co-resident).
// Per step, 4 phases split across disjoint WG sets, grid.sync() between:
//   alpha (WGs 64..127): attq = hid @ W_h.T + b_attn        (512 rows, K=1024)
//   beta  (WGs  0..31 ): scores -> softmax -> ctx (per-b)
//   gamma (WGs 128..191): xi = relu(embW + ctx @ Wc2.T)     (512 rows, K=512)
//   delta (all 256 WGs): gates = [xi|h] @ Wd.T + b_d -> LSTM update
// delta's 8 gate rows per WG are staged into LDS ONCE (constant over steps).
// Thread layout in GEMV phases: r8 = tid&7 (row), b8 = tid>>3 (batch):
// activation float4 loads are 8-lane broadcast groups (full line use),
// LDS weight reads hit 8 distinct banks (conflict-free).
// ---------------------------------------------------------------------------
__global__ __launch_bounds__(256, 1)
void k_decoder(const float* __restrict__ enc, const float* __restrict__ encp,
               const float* __restrict__ embW,
               const float* __restrict__ W_attn, const float* __restrict__ b_attn,
               const float* __restrict__ v_attn, const float* __restrict__ W_comb,
               const float* __restrict__ Wih_d, const float* __restrict__ Whh_d,
               const float* __restrict__ b_d,
               const int* __restrict__ x_lens,
               float* __restrict__ hid, float* __restrict__ xh0,
               float* __restrict__ xh1, float* __restrict__ attq,
               float* __restrict__ ctxg, float* __restrict__ Hall)
{
    cg::grid_group grid = cg::this_grid();
    const int w = blockIdx.x;
    const int tid = threadIdx.x;
    // LDS: delta weight slice (stride 1028 floats: 16B-aligned rows, banks (4r+k)%32
    // -> 8 distinct banks across the wave), beta scratch, gate transpose buffer.
    __shared__ float smemW[8 * 1028];
    __shared__ float bsc[832];
    __shared__ float g_l[8 * 33];

    // Pre-stage this WG's 8 gate rows [Wih_d | Whh_d] — constant across all steps.
    // local row lr: gate g = lr&3, hl = lr>>2; global row = 512*g + 2*w + hl.
    for (int i = tid; i < 8 * 1024; i += 256) {
        int lr = i >> 10, k = i & 1023;
        int row = 512 * (lr & 3) + 2 * w + (lr >> 2);
        smemW[lr * 1028 + k] = (k < 512) ? Wih_d[row * 512 + k]
                                         : Whh_d[row * 512 + (k - 512)];
    }
    __syncthreads();

    const int r8 = tid & 7;    // row-in-slice
    const int b8 = tid >> 3;   // batch 0..31

    for (int t = 0; t < T_; t++) {
        float* xh_cur  = (t & 1) ? xh1 : xh0;
        float* xh_next = (t & 1) ? xh0 : xh1;

        // ---- phase alpha: attq = hid @ W_h.T + b_attn  (WGs 64..127)
        if ((w >> 6) == 1) {
            int n = (w - 64) * 8 + r8;
            const float* ar = hid + b8 * 1024;
            const float* wr = W_attn + (long)n * 1536;
            float acc = 0.f;
            #pragma unroll 4
            for (int q = 0; q < 256; q++) {
                float4 a = *(const float4*)(ar + 4 * q);
                float4 v = *(const float4*)(wr + 4 * q);
                acc += a.x * v.x + a.y * v.y + a.z * v.z + a.w * v.w;
            }
            attq[b8 * 512 + n] = acc + b_attn[n];
        }
        grid.sync();

        // ---- phase beta: scores / softmax / ctx  (WGs 0..31, b = w)
        if (w < 32) {
            float* aq   = bsc;         // 512
            float* part = bsc + 512;   // 64*4
            float* p    = bsc + 768;   // 64
            aq[tid]       = attq[w * 512 + tid];
            aq[tid + 256] = attq[w * 512 + 256 + tid];
            __syncthreads();
            {
                int s = tid >> 2, q = tid & 3;
                const float* ep = encp + (long)(w * S_ + s) * 512;
                float acc = 0.f;
                #pragma unroll 4
                for (int i = 0; i < 128; i++) {
                    int e = q + 4 * i;
                    acc += v_attn[e] * tanh_fast(ep[e] + aq[e]);
                }
                part[s * 4 + q] = acc;
            }
            __syncthreads();
            if (tid < 64) {
                float sc = part[tid * 4] + part[tid * 4 + 1]
                         + part[tid * 4 + 2] + part[tid * 4 + 3];
                if (tid >= x_lens[w]) sc = -1e9f;
                float m = sc;
                for (int off = 32; off; off >>= 1) m = fmaxf(m, __shfl_xor(m, off));
                float e = __expf(sc - m);
                float sum = e;
                for (int off = 32; off; off >>= 1) sum += __shfl_xor(sum, off);
                p[tid] = e / sum;
            }
            __syncthreads();
            float c0 = 0.f, c1 = 0.f;
            for (int s2 = 0; s2 < S_; s2++) {
                float pp = p[s2];
                const float* er = enc + (long)(w * S_ + s2) * 512;
                c0 += pp * er[tid];
                c1 += pp * er[tid + 256];
            }
            ctxg[w * 512 + tid]       = c0;
            ctxg[w * 512 + 256 + tid] = c1;
        }
        grid.sync();

        // ---- phase gamma: xi = relu(embW + ctx @ Wc2.T)  (WGs 128..191)
        if ((w >> 6) == 2) {
            int n = (w - 128) * 8 + r8;
            const float* ar = ctxg + b8 * 512;
            const float* wr = W_comb + (long)n * 1024 + 512;
            float acc = 0.f;
            #pragma unroll 4
            for (int q = 0; q < 128; q++) {
                float4 a = *(const float4*)(ar + 4 * q);
                float4 v = *(const float4*)(wr + 4 * q);
                acc += a.x * v.x + a.y * v.y + a.z * v.z + a.w * v.w;
            }
            float val = acc + embW[((long)t * 32 + b8) * 512 + n];
            xh_cur[b8 * 1024 + n] = fmaxf(val, 0.f);
        }
        grid.sync();

        // ---- phase delta: gates + LSTM state update (all 256 WGs, 8 rows each)
        {
            const float* ar = xh_cur + b8 * 1024;
            const float* wl = smemW + r8 * 1028;
            float acc = 0.f;
            #pragma unroll 4
            for (int q = 0; q < 256; q++) {
                float4 a = *(const float4*)(ar + 4 * q);
                float4 v = *(const float4*)(wl + 4 * q);
                acc += a.x * v.x + a.y * v.y + a.z * v.z + a.w * v.w;
            }
            int row = 512 * (r8 & 3) + 2 * w + (r8 >> 2);
            g_l[r8 * 33 + b8] = acc + b_d[row];
            __syncthreads();
            if (tid < 64) {
                int bb = tid & 31, hl = tid >> 5;
                int hu = 2 * w + hl;
                float gi = g_l[(hl * 4 + 0) * 33 + bb];
                float gf = g_l[(hl * 4 + 1) * 33 + bb];
                float gg = g_l[(hl * 4 + 2) * 33 + bb];
                float go = g_l[(hl * 4 + 3) * 33 + bb];
                float c_old = hid[bb * 1024 + 512 + hu];
                float c_new = sigf(gf) * c_old + sigf(gi) * tanh_fast(gg);
                float h_new = sigf(go) * tanh_fast(c_new);
                hid[bb * 1024 + hu] = h_new;
                hid[bb * 1024 + 512 + hu] = c_new;
                xh_next[bb * 1024 + 512 + hu] = h_new;
                Hall[((long)bb * T_ + t) * 512 + hu] = h_new;
            }
        }
        grid.sync();
    }
}

// ---------------------------------------------------------------------------
// Per-row logsumexp over V=32000 logits (one WG per row).
// ---------------------------------------------------------------------------
__global__ __launch_bounds__(256)
void k_lse(const float* __restrict__ Cl, float* __restrict__ lse)
{
    const int r = blockIdx.x;
    const float* row = Cl + (long)r * V_;
    const int tid = threadIdx.x;
    __shared__ float red[4];
    float m = -1e30f;
    for (int i = tid; i < V_; i += 256) m = fmaxf(m, row[i]);
    for (int off = 32; off; off >>= 1) m = fmaxf(m, __shfl_xor(m, off));
    int w = tid >> 6;
    if ((tid & 63) == 0) red[w] = m;
    __syncthreads();
    m = fmaxf(fmaxf(red[0], red[1]), fmaxf(red[2], red[3]));
    __syncthreads();
    float s = 0.f;
    for (int i = tid; i < V_; i += 256) s += __expf(row[i] - m);
    for (int off = 32; off; off >>= 1) s += __shfl_xor(s, off);
    if ((tid & 63) == 0) red[w] = s;
    __syncthreads();
    if (tid == 0) {
        s = red[0] + red[1] + red[2] + red[3];
        lse[r] = m + __logf(s);
    }
}

__global__ void k_logsub(float* __restrict__ C, const float* __restrict__ lse)
{
    long n4 = (long)2048 * V_ / 4;
    long stride = (long)gridDim.x * blockDim.x;
    for (long i = (long)blockIdx.x * blockDim.x + threadIdx.x; i < n4; i += stride) {
        float4 v = ((float4*)C)[i];
        float l = lse[(i * 4) / V_];
        v.x -= l; v.y -= l; v.z -= l; v.w -= l;
        ((float4*)C)[i] = v;
    }
}

// ---------------------------------------------------------------------------
extern "C" void kernel_launch(void* const* d_in, const int* in_sizes, int n_in,
                              void* d_out, int out_size, void* d_ws, size_t ws_size,
                              hipStream_t stream)
{
    const int*   xs     = (const int*)  d_in[0];
    const int*   x_lens = (const int*)  d_in[1];
    const int*   ys     = (const int*)  d_in[2];
    const float* src_emb= (const float*)d_in[3];
    const float* W_tr   = (const float*)d_in[4];
    const float* b_tr   = (const float*)d_in[5];
    const float* Wih_f  = (const float*)d_in[6];
    const float* Whh_f  = (const float*)d_in[7];
    const float* b_f    = (const float*)d_in[8];
    const float* Wih_b  = (const float*)d_in[9];
    const float* Whh_b  = (const float*)d_in[10];
    const float* b_b    = (const float*)d_in[11];
    const float* W_attn = (const float*)d_in[12];
    const float* b_attn = (const float*)d_in[13];
    const float* v_attn = (const float*)d_in[14];
    const float* tgt_emb= (const float*)d_in[15];
    const float* W_comb = (const float*)d_in[16];
    const float* b_comb = (const float*)d_in[17];
    const float* Wih_d  = (const float*)d_in[18];
    const float* Whh_d  = (const float*)d_in[19];
    const float* b_d    = (const float*)d_in[20];
    const float* W_out  = (const float*)d_in[21];
    const float* b_out  = (const float*)d_in[22];
    float* out = (float*)d_out;

    float* ws = (float*)d_ws;
    size_t off = 0;
    auto alloc = [&](size_t n) { float* p = ws + off; off += n; return p; };
    float* x      = alloc(2048 * 512);
    float* gpre_f = alloc(2048 * 1024);
    float* gpre_b = alloc(2048 * 1024);
    float* enc    = alloc(2048 * 512);
    float* encp   = alloc(2048 * 512);
    float* embW   = alloc(2048 * 512);
    float* Hall   = alloc(2048 * 512);
    float* hid    = alloc(32 * 1024);
    float* xh0    = alloc(32 * 1024);
    float* xh1    = alloc(32 * 1024);
    float* attq   = alloc(32 * 512);
    float* ctx    = alloc(32 * 512);
    float* WhhTf  = alloc(256 * 1024);
    float* WhhTb  = alloc(256 * 1024);
    float* lse    = alloc(2048);
    int*   tokens = (int*)alloc(2048);
    (void)ws_size; (void)n_in; (void)in_sizes; (void)out_size;

    // prep
    k_prep<<<512, 256, 0, stream>>>(ys, Whh_f, Whh_b, WhhTf, WhhTb, tokens);

    // x = src_emb[xs] @ W_tr.T + b_tr   (M=2048, N=512, K=768)
    gemm_f32<<<dim3(512 / 64, 2048 / 64), 256, 0, stream>>>(src_emb, xs, P_, W_tr, P_, 0, b_tr, x, 512, P_);
    // gpre_f/b = x @ Wih.T + b          (M=2048, N=1024, K=512)
    gemm_f32<<<dim3(1024 / 64, 2048 / 64), 256, 0, stream>>>(x, nullptr, 512, Wih_f, 512, 0, b_f, gpre_f, 1024, 512);
    gemm_f32<<<dim3(1024 / 64, 2048 / 64), 256, 0, stream>>>(x, nullptr, 512, Wih_b, 512, 0, b_b, gpre_b, 1024, 512);

    // encoder recurrence
    k_encoder<<<64, 1024, 0, stream>>>(gpre_f, gpre_b, WhhTf, WhhTb, x_lens, enc, hid, xh0);

    // enc_proj = enc @ W_e.T            (W_attn cols 1024:1536, no bias)
    gemm_f32<<<dim3(512 / 64, 2048 / 64), 256, 0, stream>>>(enc, nullptr, 512, W_attn, 1536, 1024, nullptr, encp, 512, 512);
    // embW = tgt_emb[tokens] @ W_comb[:, :512].T + b_comb   (rows = t*32+b)
    gemm_f32<<<dim3(512 / 64, 2048 / 64), 256, 0, stream>>>(tgt_emb, tokens, 512, W_comb, 1024, 0, b_comb, embW, 512, 512);

    // fused persistent decoder (all 64 steps, cooperative launch)
    {
        void* args[] = { (void*)&enc, (void*)&encp, (void*)&embW, (void*)&W_attn,
                         (void*)&b_attn, (void*)&v_attn, (void*)&W_comb,
                         (void*)&Wih_d, (void*)&Whh_d, (void*)&b_d, (void*)&x_lens,
                         (void*)&hid, (void*)&xh0, (void*)&xh1, (void*)&attq,
                         (void*)&ctx, (void*)&Hall };
        hipLaunchCooperativeKernel((void*)k_decoder, dim3(256), dim3(256), args, 0, stream);
    }

    // logits = Hall @ W_out.T + b_out  -> d_out   (M=2048, N=32000, K=512)
    gemm_f32<<<dim3(V_ / 64, 2048 / 64), 256, 0, stream>>>(Hall, nullptr, 512, W_out, 512, 0, b_out, out, V_, 512);
    // log_softmax
    k_lse<<<2048, 256, 0, stream>>>(out, lse);
    k_logsub<<<8192, 256, 0, stream>>>(out, lse);
}

// Round 2
// 8328.443 us; speedup vs baseline: 1.8013x; 1.8013x over previous
//
#include <hip/hip_runtime.h>
#include <math.h>

#define B_  32
#define S_  64
#define T_  64
#define P_  768
#define E_  512
#define H2_ 256
#define G2_ 1024
#define HD_ 512
#define V_  32000
#define NWG 256

__device__ __forceinline__ float sigf(float x) {
    return 1.0f / (1.0f + __expf(-x));
}
__device__ __forceinline__ float tanh_fast(float x) {
    // tanh(x) = 1 - 2/(exp(2x)+1); exact limits at +-inf
    return 1.0f - 2.0f / (__expf(2.0f * x) + 1.0f);
}

// ---------------------------------------------------------------------------
// prep: transpose Whh_f/Whh_b to [k][gate]; tokens; zero grid-barrier state
// ---------------------------------------------------------------------------
__global__ void k_prep(const int* __restrict__ ys,
                       const float* __restrict__ Whh_f, const float* __restrict__ Whh_b,
                       float* __restrict__ WhhT_f, float* __restrict__ WhhT_b,
                       int* __restrict__ tokens, unsigned* __restrict__ bar)
{
    int i = blockIdx.x * blockDim.x + threadIdx.x;
    int n = gridDim.x * blockDim.x;
    for (int idx = i; idx < G2_ * H2_; idx += n) {
        int k = idx / G2_, g = idx % G2_;
        WhhT_f[idx] = Whh_f[g * H2_ + k];
        WhhT_b[idx] = Whh_b[g * H2_ + k];
    }
    for (int idx = i; idx < T_ * B_; idx += n) {
        int t = idx / B_, b = idx % B_;
        tokens[idx] = (t == 0) ? 1 : ys[b * (T_ + 1) + t];
    }
    for (int idx = i; idx < 160; idx += n) bar[idx] = 0u;
}

// ---------------------------------------------------------------------------
// Tiled fp32 GEMM:  C[m,n] = bias[n] + sum_k A(m)[k] * W[n*ldw + woff + k]
// ---------------------------------------------------------------------------
__global__ __launch_bounds__(256)
void gemm_f32(const float* __restrict__ A, const int* __restrict__ gidx, int lda,
              const float* __restrict__ W, int ldw, int woff,
              const float* __restrict__ bias,
              float* __restrict__ C, int ldc, int K)
{
    __shared__ __align__(16) float As[16][64];
    __shared__ __align__(16) float Bs[16][64];
    const int m0 = blockIdx.y * 64;
    const int n0 = blockIdx.x * 64;
    const int tid = threadIdx.x;
    const int tm = tid & 15, tn = tid >> 4;
    const int la_m = tid >> 2;        // 0..63
    const int la_k = (tid & 3) * 4;   // 0,4,8,12
    float acc[4][4] = {};

    const int am = m0 + la_m;
    const float* arow = A + (long)(gidx ? gidx[am] : am) * lda;
    const float* wrow = W + (long)(n0 + la_m) * ldw + woff;

    for (int k0 = 0; k0 < K; k0 += 16) {
        float4 av = *(const float4*)(arow + k0 + la_k);
        float4 wv = *(const float4*)(wrow + k0 + la_k);
        As[la_k + 0][la_m] = av.x; As[la_k + 1][la_m] = av.y;
        As[la_k + 2][la_m] = av.z; As[la_k + 3][la_m] = av.w;
        Bs[la_k + 0][la_m] = wv.x; Bs[la_k + 1][la_m] = wv.y;
        Bs[la_k + 2][la_m] = wv.z; Bs[la_k + 3][la_m] = wv.w;
        __syncthreads();
        #pragma unroll
        for (int kk = 0; kk < 16; kk++) {
            float4 a = *(const float4*)&As[kk][tm * 4];
            float4 b = *(const float4*)&Bs[kk][tn * 4];
            acc[0][0] += a.x * b.x; acc[0][1] += a.x * b.y; acc[0][2] += a.x * b.z; acc[0][3] += a.x * b.w;
            acc[1][0] += a.y * b.x; acc[1][1] += a.y * b.y; acc[1][2] += a.y * b.z; acc[1][3] += a.y * b.w;
            acc[2][0] += a.z * b.x; acc[2][1] += a.z * b.y; acc[2][2] += a.z * b.z; acc[2][3] += a.z * b.w;
            acc[3][0] += a.w * b.x; acc[3][1] += a.w * b.y; acc[3][2] += a.w * b.z; acc[3][3] += a.w * b.w;
        }
        __syncthreads();
    }
    float b0 = bias ? bias[n0 + tn * 4 + 0] : 0.f;
    float b1 = bias ? bias[n0 + tn * 4 + 1] : 0.f;
    float b2 = bias ? bias[n0 + tn * 4 + 2] : 0.f;
    float b3 = bias ? bias[n0 + tn * 4 + 3] : 0.f;
    #pragma unroll
    for (int i = 0; i < 4; i++) {
        long m = m0 + tm * 4 + i;
        float4 o = make_float4(acc[i][0] + b0, acc[i][1] + b1, acc[i][2] + b2, acc[i][3] + b3);
        *(float4*)&C[m * ldc + n0 + tn * 4] = o;
    }
}

// ---------------------------------------------------------------------------
// BiLSTM encoder recurrence: one WG per (b, dir); 1024 threads (one per gate).
// ---------------------------------------------------------------------------
__global__ __launch_bounds__(1024)
void k_encoder(const float* __restrict__ gpre_f, const float* __restrict__ gpre_b,
               const float* __restrict__ WhhT_f, const float* __restrict__ WhhT_b,
               const int* __restrict__ x_lens,
               float* __restrict__ enc, float* __restrict__ hid, float* __restrict__ xh0)
{
    const int b   = blockIdx.x >> 1;
    const int dir = blockIdx.x & 1;
    const float* gpre = dir ? gpre_b : gpre_f;
    const float* WT   = dir ? WhhT_b : WhhT_f;
    const int len = x_lens[b];
    __shared__ float h_lds[H2_];
    __shared__ float g_lds[G2_];
    const int tid = threadIdx.x;
    float c = 0.f;
    if (tid < H2_) h_lds[tid] = 0.f;
    __syncthreads();

    for (int t = 0; t < S_; t++) {
        bool valid = t < len;
        if (valid) {
            int s_in = dir ? (len - 1 - t) : t;
            float acc = gpre[(long)(b * S_ + s_in) * G2_ + tid];
            #pragma unroll 8
            for (int k = 0; k < H2_; k++)
                acc += h_lds[k] * WT[k * G2_ + tid];
            g_lds[tid] = acc;
            __syncthreads();
            if (tid < H2_) {
                float gi = g_lds[tid], gf = g_lds[H2_ + tid];
                float gg = g_lds[2 * H2_ + tid], go = g_lds[3 * H2_ + tid];
                c = sigf(gf) * c + sigf(gi) * tanh_fast(gg);
                float hn = sigf(go) * tanh_fast(c);
                h_lds[tid] = hn;
                enc[(long)(b * S_ + s_in) * E_ + dir * H2_ + tid] = hn;
            }
            __syncthreads();
        } else {
            if (tid < H2_)
                enc[(long)(b * S_ + t) * E_ + dir * H2_ + tid] = 0.f;
        }
    }
    if (tid < H2_) {
        hid[b * 1024 + dir * H2_ + tid]       = h_lds[tid]; // h
        hid[b * 1024 + 512 + dir * H2_ + tid] = c;          // c
        xh0[b * 1024 + 512 + dir * H2_ + tid] = h_lds[tid]; // h for gates step 0
    }
}

// ---------------------------------------------------------------------------
// Hand-rolled two-level grid barrier (monotonic counters, no reset races).
//  bar[16*g], g=0..7 : sub-counters (one cacheline apart; 32 WGs each)
//  bar[128]          : master counter (8 increments per barrier instance)
//  bar[144]          : release generation
// Producer visibility: __syncthreads() drains each wave's stores to L2;
// lane0's __threadfence() (agent scope) writes back L2 (covers whole WG's
// stores) before arrival; acquire __threadfence() after wake invalidates L2.
// ---------------------------------------------------------------------------
__device__ __forceinline__ void grid_bar(unsigned* bar, int w, int tid)
{
    __syncthreads();
    if (tid == 0) {
        __threadfence();   // release: wbl2 pushes this WG's stores to IF/L3
        unsigned a = __hip_atomic_fetch_add(&bar[16 * (w & 7)], 1u,
                        __ATOMIC_RELAXED, __HIP_MEMORY_SCOPE_AGENT);
        unsigned target = (a >> 5) + 1u;      // barrier instance this completes
        if ((a & 31u) == 31u) {               // last of 32 in this sub-group
            unsigned m = __hip_atomic_fetch_add(&bar[128], 1u,
                            __ATOMIC_RELAXED, __HIP_MEMORY_SCOPE_AGENT);
            if ((m & 7u) == 7u)               // last sub-group overall
                __hip_atomic_store(&bar[144], (m >> 3) + 1u,
                                   __ATOMIC_RELAXED, __HIP_MEMORY_SCOPE_AGENT);
        }
        while (__hip_atomic_load(&bar[144], __ATOMIC_RELAXED,
                                 __HIP_MEMORY_SCOPE_AGENT) < target)
            __builtin_amdgcn_s_sleep(8);
        __threadfence();   // acquire: invalidate L2 so fresh data is re-fetched
    }
    __syncthreads();
}

// ---------------------------------------------------------------------------
// Fused persistent decoder, hand-rolled barriers, ALL weights LDS-resident.
// Grid = 256 WGs x 256 threads, 1 WG/CU (63.1 KB static LDS).
// Per step (4 barriers):
//  alpha (all WGs): attq = hid @ W_h.T + b_attn; WG w owns rows 4*(w>>1)+0..3,
//         batches 16*(w&1)+0..15; K=1024 split 4-ways across threads.
//  beta  (WGs 0..31): scores -> softmax -> ctx (per-batch, verified code).
//  gamma (all WGs): xi = relu(embW + ctx @ Wc2.T); same split, K=512.
//  delta (all WGs): gates = [xi|h] @ Wd.T + b_d -> LSTM update; WG owns 8 gate
//         rows x all 32 batches (Wd slice LDS-resident).
// ---------------------------------------------------------------------------
__global__ __launch_bounds__(256, 1)
void k_decoder(const float* __restrict__ enc, const float* __restrict__ encp,
               const float* __restrict__ embW,
               const float* __restrict__ W_attn, const float* __restrict__ b_attn,
               const float* __restrict__ v_attn, const float* __restrict__ W_comb,
               const float* __restrict__ Wih_d, const float* __restrict__ Whh_d,
               const float* __restrict__ b_d,
               const int* __restrict__ x_lens,
               float* __restrict__ hid, float* __restrict__ xh0,
               float* __restrict__ xh1, float* __restrict__ attq,
               float* __restrict__ ctxg, float* __restrict__ Hall,
               unsigned* __restrict__ bar)
{
    const int w = blockIdx.x;
    const int tid = threadIdx.x;

    // LDS strides padded so multi-row reads spread across bank groups.
    __shared__ float WdL[8 * 1028];   // 32896 B: 8 decoder-gate rows (K=1024)
    __shared__ float WhL[4 * 1032];   // 16512 B: 4 W_h rows (K=1024)
    __shared__ float WcL[4 * 520];    //  8320 B: 4 Wc2 rows (K=512)
    __shared__ float red[256];        //  1024 B: alpha/gamma partial sums
    __shared__ float bsc[832];        //  3328 B: beta scratch
    __shared__ float g_l[8 * 33];     //  1056 B: delta gate transpose
    // total = 63136 B

    // ---- stage weights once (immune to per-barrier L2 invalidation) ----
    for (int i = tid; i < 8 * 1024; i += 256) {
        int lr = i >> 10, k = i & 1023;
        int row = 512 * (lr & 3) + 2 * w + (lr >> 2);
        WdL[lr * 1028 + k] = (k < 512) ? Wih_d[row * 512 + k]
                                       : Whh_d[row * 512 + (k - 512)];
    }
    for (int i = tid; i < 4 * 1024; i += 256) {
        int lr = i >> 10, k = i & 1023;
        WhL[lr * 1032 + k] = W_attn[(long)(4 * (w >> 1) + lr) * 1536 + k];
    }
    for (int i = tid; i < 4 * 512; i += 256) {
        int lr = i >> 9, k = i & 511;
        WcL[lr * 520 + k] = W_comb[(long)(4 * (w >> 1) + lr) * 1024 + 512 + k];
    }
    __syncthreads();

    const int o  = tid >> 2;            // 0..63 output slot (alpha/gamma)
    const int ks = tid & 3;             // K-quarter
    const int bl = o >> 2, lr = o & 3;
    const int ab = 16 * (w & 1) + bl;   // batch for alpha/gamma
    const int an = 4 * (w >> 1) + lr;   // output row for alpha/gamma
    const int r8 = tid & 7, b8 = tid >> 3;  // delta mapping

    for (int t = 0; t < T_; t++) {
        float* xh_cur  = (t & 1) ? xh1 : xh0;
        float* xh_next = (t & 1) ? xh0 : xh1;

        // ---- alpha: attq[b][n] = b_attn[n] + hid[b] . W_h[n]
        {
            const float* hr = hid + ab * 1024;
            const float* wr = WhL + lr * 1032;
            float acc = 0.f;
            #pragma unroll 8
            for (int i = 0; i < 64; i++) {
                int k = 16 * i + 4 * ks;
                float4 a = *(const float4*)(hr + k);
                float4 v = *(const float4*)(wr + k);
                acc += a.x * v.x + a.y * v.y + a.z * v.z + a.w * v.w;
            }
            red[tid] = acc;
            __syncthreads();
            if (tid < 64) {
                int b2 = 16 * (w & 1) + (tid >> 2);
                int n2 = 4 * (w >> 1) + (tid & 3);
                float s = red[tid * 4] + red[tid * 4 + 1]
                        + red[tid * 4 + 2] + red[tid * 4 + 3];
                attq[b2 * 512 + n2] = s + b_attn[n2];
            }
        }
        grid_bar(bar, w, tid);

        // ---- beta: scores / softmax / ctx  (WGs 0..31, b = w)
        if (w < 32) {
            float* aq   = bsc;         // 512
            float* part = bsc + 512;   // 64*4
            float* p    = bsc + 768;   // 64
            aq[tid]       = attq[w * 512 + tid];
            aq[tid + 256] = attq[w * 512 + 256 + tid];
            __syncthreads();
            {
                int s = tid >> 2, q = tid & 3;
                const float* ep = encp + (long)(w * S_ + s) * 512;
                float acc = 0.f;
                #pragma unroll 4
                for (int i = 0; i < 128; i++) {
                    int e = q + 4 * i;
                    acc += v_attn[e] * tanh_fast(ep[e] + aq[e]);
                }
                part[s * 4 + q] = acc;
            }
            __syncthreads();
            if (tid < 64) {
                float sc = part[tid * 4] + part[tid * 4 + 1]
                         + part[tid * 4 + 2] + part[tid * 4 + 3];
                if (tid >= x_lens[w]) sc = -1e9f;
                float m = sc;
                for (int off = 32; off; off >>= 1) m = fmaxf(m, __shfl_xor(m, off));
                float e = __expf(sc - m);
                float sum = e;
                for (int off = 32; off; off >>= 1) sum += __shfl_xor(sum, off);
                p[tid] = e / sum;
            }
            __syncthreads();
            float c0 = 0.f, c1 = 0.f;
            for (int s2 = 0; s2 < S_; s2++) {
                float pp = p[s2];
                const float* er = enc + (long)(w * S_ + s2) * 512;
                c0 += pp * er[tid];
                c1 += pp * er[tid + 256];
            }
            ctxg[w * 512 + tid]       = c0;
            ctxg[w * 512 + 256 + tid] = c1;
        }
        grid_bar(bar, w, tid);

        // ---- gamma: xi = relu(embW + ctx @ Wc2.T)
        {
            const float* cr = ctxg + ab * 512;
            const float* wr = WcL + lr * 520;
            float acc = 0.f;
            #pragma unroll 8
            for (int i = 0; i < 32; i++) {
                int k = 16 * i + 4 * ks;
                float4 a = *(const float4*)(cr + k);
                float4 v = *(const float4*)(wr + k);
                acc += a.x * v.x + a.y * v.y + a.z * v.z + a.w * v.w;
            }
            red[tid] = acc;
            __syncthreads();
            if (tid < 64) {
                int b2 = 16 * (w & 1) + (tid >> 2);
                int n2 = 4 * (w >> 1) + (tid & 3);
                float s = red[tid * 4] + red[tid * 4 + 1]
                        + red[tid * 4 + 2] + red[tid * 4 + 3];
                float val = s + embW[((long)t * 32 + b2) * 512 + n2];
                xh_cur[b2 * 1024 + n2] = fmaxf(val, 0.f);
            }
        }
        grid_bar(bar, w, tid);

        // ---- delta: gates + LSTM state update (8 gate rows x 32 batches)
        {
            const float* ar = xh_cur + b8 * 1024;
            const float* wl = WdL + r8 * 1028;
            float acc = 0.f;
            #pragma unroll 8
            for (int q = 0; q < 256; q++) {
                float4 a = *(const float4*)(ar + 4 * q);
                float4 v = *(const float4*)(wl + 4 * q);
                acc += a.x * v.x + a.y * v.y + a.z * v.z + a.w * v.w;
            }
            int row = 512 * (r8 & 3) + 2 * w + (r8 >> 2);
            g_l[r8 * 33 + b8] = acc + b_d[row];
            __syncthreads();
            if (tid < 64) {
                int bb = tid & 31, hl = tid >> 5;
                int hu = 2 * w + hl;
                float gi = g_l[(hl * 4 + 0) * 33 + bb];
                float gf = g_l[(hl * 4 + 1) * 33 + bb];
                float gg = g_l[(hl * 4 + 2) * 33 + bb];
                float go = g_l[(hl * 4 + 3) * 33 + bb];
                float c_old = hid[bb * 1024 + 512 + hu];
                float c_new = sigf(gf) * c_old + sigf(gi) * tanh_fast(gg);
                float h_new = sigf(go) * tanh_fast(c_new);
                hid[bb * 1024 + hu] = h_new;
                hid[bb * 1024 + 512 + hu] = c_new;
                xh_next[bb * 1024 + 512 + hu] = h_new;
                Hall[((long)bb * T_ + t) * 512 + hu] = h_new;
            }
        }
        grid_bar(bar, w, tid);
    }
}

// ---------------------------------------------------------------------------
// Per-row logsumexp over V=32000 logits (one WG per row).
// ---------------------------------------------------------------------------
__global__ __launch_bounds__(256)
void k_lse(const float* __restrict__ Cl, float* __restrict__ lse)
{
    const int r = blockIdx.x;
    const float* row = Cl + (long)r * V_;
    const int tid = threadIdx.x;
    __shared__ float red[4];
    float m = -1e30f;
    for (int i = tid; i < V_; i += 256) m = fmaxf(m, row[i]);
    for (int off = 32; off; off >>= 1) m = fmaxf(m, __shfl_xor(m, off));
    int w = tid >> 6;
    if ((tid & 63) == 0) red[w] = m;
    __syncthreads();
    m = fmaxf(fmaxf(red[0], red[1]), fmaxf(red[2], red[3]));
    __syncthreads();
    float s = 0.f;
    for (int i = tid; i < V_; i += 256) s += __expf(row[i] - m);
    for (int off = 32; off; off >>= 1) s += __shfl_xor(s, off);
    if ((tid & 63) == 0) red[w] = s;
    __syncthreads();
    if (tid == 0) {
        s = red[0] + red[1] + red[2] + red[3];
        lse[r] = m + __logf(s);
    }
}

__global__ void k_logsub(float* __restrict__ C, const float* __restrict__ lse)
{
    long n4 = (long)2048 * V_ / 4;
    long stride = (long)gridDim.x * blockDim.x;
    for (long i = (long)blockIdx.x * blockDim.x + threadIdx.x; i < n4; i += stride) {
        float4 v = ((float4*)C)[i];
        float l = lse[(i * 4) / V_];
        v.x -= l; v.y -= l; v.z -= l; v.w -= l;
        ((float4*)C)[i] = v;
    }
}

// ---------------------------------------------------------------------------
extern "C" void kernel_launch(void* const* d_in, const int* in_sizes, int n_in,
                              void* d_out, int out_size, void* d_ws, size_t ws_size,
                              hipStream_t stream)
{
    const int*   xs     = (const int*)  d_in[0];
    const int*   x_lens = (const int*)  d_in[1];
    const int*   ys     = (const int*)  d_in[2];
    const float* src_emb= (const float*)d_in[3];
    const float* W_tr   = (const float*)d_in[4];
    const float* b_tr   = (const float*)d_in[5];
    const float* Wih_f  = (const float*)d_in[6];
    const float* Whh_f  = (const float*)d_in[7];
    const float* b_f    = (const float*)d_in[8];
    const float* Wih_b  = (const float*)d_in[9];
    const float* Whh_b  = (const float*)d_in[10];
    const float* b_b    = (const float*)d_in[11];
    const float* W_attn = (const float*)d_in[12];
    const float* b_attn = (const float*)d_in[13];
    const float* v_attn = (const float*)d_in[14];
    const float* tgt_emb= (const float*)d_in[15];
    const float* W_comb = (const float*)d_in[16];
    const float* b_comb = (const float*)d_in[17];
    const float* Wih_d  = (const float*)d_in[18];
    const float* Whh_d  = (const float*)d_in[19];
    const float* b_d    = (const float*)d_in[20];
    const float* W_out  = (const float*)d_in[21];
    const float* b_out  = (const float*)d_in[22];
    float* out = (float*)d_out;

    float* ws = (float*)d_ws;
    size_t off = 0;
    auto alloc = [&](size_t n) { float* p = ws + off; off += n; return p; };
    float* x      = alloc(2048 * 512);
    float* gpre_f = alloc(2048 * 1024);
    float* gpre_b = alloc(2048 * 1024);
    float* enc    = alloc(2048 * 512);
    float* encp   = alloc(2048 * 512);
    float* embW   = alloc(2048 * 512);
    float* Hall   = alloc(2048 * 512);
    float* hid    = alloc(32 * 1024);
    float* xh0    = alloc(32 * 1024);
    float* xh1    = alloc(32 * 1024);
    float* attq   = alloc(32 * 512);
    float* ctx    = alloc(32 * 512);
    float* WhhTf  = alloc(256 * 1024);
    float* WhhTb  = alloc(256 * 1024);
    float* lse    = alloc(2048);
    int*   tokens = (int*)alloc(2048);
    unsigned* bar = (unsigned*)alloc(160);
    (void)ws_size; (void)n_in; (void)in_sizes; (void)out_size;

    // prep (also zeroes the grid-barrier state each launch/replay)
    k_prep<<<512, 256, 0, stream>>>(ys, Whh_f, Whh_b, WhhTf, WhhTb, tokens, bar);

    // x = src_emb[xs] @ W_tr.T + b_tr   (M=2048, N=512, K=768)
    gemm_f32<<<dim3(512 / 64, 2048 / 64), 256, 0, stream>>>(src_emb, xs, P_, W_tr, P_, 0, b_tr, x, 512, P_);
    // gpre_f/b = x @ Wih.T + b          (M=2048, N=1024, K=512)
    gemm_f32<<<dim3(1024 / 64, 2048 / 64), 256, 0, stream>>>(x, nullptr, 512, Wih_f, 512, 0, b_f, gpre_f, 1024, 512);
    gemm_f32<<<dim3(1024 / 64, 2048 / 64), 256, 0, stream>>>(x, nullptr, 512, Wih_b, 512, 0, b_b, gpre_b, 1024, 512);

    // encoder recurrence
    k_encoder<<<64, 1024, 0, stream>>>(gpre_f, gpre_b, WhhTf, WhhTb, x_lens, enc, hid, xh0);

    // enc_proj = enc @ W_e.T            (W_attn cols 1024:1536, no bias)
    gemm_f32<<<dim3(512 / 64, 2048 / 64), 256, 0, stream>>>(enc, nullptr, 512, W_attn, 1536, 1024, nullptr, encp, 512, 512);
    // embW = tgt_emb[tokens] @ W_comb[:, :512].T + b_comb   (rows = t*32+b)
    gemm_f32<<<dim3(512 / 64, 2048 / 64), 256, 0, stream>>>(tgt_emb, tokens, 512, W_comb, 1024, 0, b_comb, embW, 512, 512);

    // fused persistent decoder (all 64 steps, cooperative launch,
    // hand-rolled grid barriers, LDS-resident weights)
    {
        void* args[] = { (void*)&enc, (void*)&encp, (void*)&embW, (void*)&W_attn,
                         (void*)&b_attn, (void*)&v_attn, (void*)&W_comb,
                         (void*)&Wih_d, (void*)&Whh_d, (void*)&b_d, (void*)&x_lens,
                         (void*)&hid, (void*)&xh0, (void*)&xh1, (void*)&attq,
                         (void*)&ctx, (void*)&Hall, (void*)&bar };
        hipLaunchCooperativeKernel((void*)k_decoder, dim3(NWG), dim3(256), args, 0, stream);
    }

    // logits = Hall @ W_out.T + b_out  -> d_out   (M=2048, N=32000, K=512)
    gemm_f32<<<dim3(V_ / 64, 2048 / 64), 256, 0, stream>>>(Hall, nullptr, 512, W_out, 512, 0, b_out, out, V_, 512);
    // log_softmax
    k_lse<<<2048, 256, 0, stream>>>(out, lse);
    k_logsub<<<8192, 256, 0, stream>>>(out, lse);
}

// Round 4
// 8290.271 us; speedup vs baseline: 1.8096x; 1.0046x over previous
//
#include <hip/hip_runtime.h>
#include <math.h>

#define B_  32
#define S_  64
#define T_  64
#define P_  768
#define E_  512
#define H2_ 256
#define G2_ 1024
#define HD_ 512
#define V_  32000
#define NWG 256

__device__ __forceinline__ float sigf(float x) {
    return 1.0f / (1.0f + __expf(-x));
}
__device__ __forceinline__ float tanh_fast(float x) {
    // tanh(x) = 1 - 2/(exp(2x)+1); exact limits at +-inf
    return 1.0f - 2.0f / (__expf(2.0f * x) + 1.0f);
}

// Agent-scope (sc1, L2-bypass) accessors for cross-WG data. These are
// coherent at the mall without any cache flush/invalidate.
__device__ __forceinline__ float ld1(const float* p) {
    return __hip_atomic_load(p, __ATOMIC_RELAXED, __HIP_MEMORY_SCOPE_AGENT);
}
__device__ __forceinline__ float2 ld2(const float* p) {
    union { unsigned long long u; float2 f; } v;
    v.u = __hip_atomic_load((const unsigned long long*)p,
                            __ATOMIC_RELAXED, __HIP_MEMORY_SCOPE_AGENT);
    return v.f;
}
__device__ __forceinline__ void st1(float* p, float v) {
    __hip_atomic_store(p, v, __ATOMIC_RELAXED, __HIP_MEMORY_SCOPE_AGENT);
}

// ---------------------------------------------------------------------------
// prep: transpose Whh_f/Whh_b to [k][gate]; tokens; zero grid-barrier state
// ---------------------------------------------------------------------------
__global__ void k_prep(const int* __restrict__ ys,
                       const float* __restrict__ Whh_f, const float* __restrict__ Whh_b,
                       float* __restrict__ WhhT_f, float* __restrict__ WhhT_b,
                       int* __restrict__ tokens, unsigned* __restrict__ bar)
{
    int i = blockIdx.x * blockDim.x + threadIdx.x;
    int n = gridDim.x * blockDim.x;
    for (int idx = i; idx < G2_ * H2_; idx += n) {
        int k = idx / G2_, g = idx % G2_;
        WhhT_f[idx] = Whh_f[g * H2_ + k];
        WhhT_b[idx] = Whh_b[g * H2_ + k];
    }
    for (int idx = i; idx < T_ * B_; idx += n) {
        int t = idx / B_, b = idx % B_;
        tokens[idx] = (t == 0) ? 1 : ys[b * (T_ + 1) + t];
    }
    for (int idx = i; idx < 160; idx += n) bar[idx] = 0u;
}

// ---------------------------------------------------------------------------
// Tiled fp32 GEMM:  C[m,n] = bias[n] + sum_k A(m)[k] * W[n*ldw + woff + k]
// ---------------------------------------------------------------------------
__global__ __launch_bounds__(256)
void gemm_f32(const float* __restrict__ A, const int* __restrict__ gidx, int lda,
              const float* __restrict__ W, int ldw, int woff,
              const float* __restrict__ bias,
              float* __restrict__ C, int ldc, int K)
{
    __shared__ __align__(16) float As[16][64];
    __shared__ __align__(16) float Bs[16][64];
    const int m0 = blockIdx.y * 64;
    const int n0 = blockIdx.x * 64;
    const int tid = threadIdx.x;
    const int tm = tid & 15, tn = tid >> 4;
    const int la_m = tid >> 2;        // 0..63
    const int la_k = (tid & 3) * 4;   // 0,4,8,12
    float acc[4][4] = {};

    const int am = m0 + la_m;
    const float* arow = A + (long)(gidx ? gidx[am] : am) * lda;
    const float* wrow = W + (long)(n0 + la_m) * ldw + woff;

    for (int k0 = 0; k0 < K; k0 += 16) {
        float4 av = *(const float4*)(arow + k0 + la_k);
        float4 wv = *(const float4*)(wrow + k0 + la_k);
        As[la_k + 0][la_m] = av.x; As[la_k + 1][la_m] = av.y;
        As[la_k + 2][la_m] = av.z; As[la_k + 3][la_m] = av.w;
        Bs[la_k + 0][la_m] = wv.x; Bs[la_k + 1][la_m] = wv.y;
        Bs[la_k + 2][la_m] = wv.z; Bs[la_k + 3][la_m] = wv.w;
        __syncthreads();
        #pragma unroll
        for (int kk = 0; kk < 16; kk++) {
            float4 a = *(const float4*)&As[kk][tm * 4];
            float4 b = *(const float4*)&Bs[kk][tn * 4];
            acc[0][0] += a.x * b.x; acc[0][1] += a.x * b.y; acc[0][2] += a.x * b.z; acc[0][3] += a.x * b.w;
            acc[1][0] += a.y * b.x; acc[1][1] += a.y * b.y; acc[1][2] += a.y * b.z; acc[1][3] += a.y * b.w;
            acc[2][0] += a.z * b.x; acc[2][1] += a.z * b.y; acc[2][2] += a.z * b.z; acc[2][3] += a.z * b.w;
            acc[3][0] += a.w * b.x; acc[3][1] += a.w * b.y; acc[3][2] += a.w * b.z; acc[3][3] += a.w * b.w;
        }
        __syncthreads();
    }
    float b0 = bias ? bias[n0 + tn * 4 + 0] : 0.f;
    float b1 = bias ? bias[n0 + tn * 4 + 1] : 0.f;
    float b2 = bias ? bias[n0 + tn * 4 + 2] : 0.f;
    float b3 = bias ? bias[n0 + tn * 4 + 3] : 0.f;
    #pragma unroll
    for (int i = 0; i < 4; i++) {
        long m = m0 + tm * 4 + i;
        float4 o = make_float4(acc[i][0] + b0, acc[i][1] + b1, acc[i][2] + b2, acc[i][3] + b3);
        *(float4*)&C[m * ldc + n0 + tn * 4] = o;
    }
}

// ---------------------------------------------------------------------------
// BiLSTM encoder recurrence: one WG per (b, dir); 1024 threads (one per gate).
// ---------------------------------------------------------------------------
__global__ __launch_bounds__(1024)
void k_encoder(const float* __restrict__ gpre_f, const float* __restrict__ gpre_b,
               const float* __restrict__ WhhT_f, const float* __restrict__ WhhT_b,
               const int* __restrict__ x_lens,
               float* __restrict__ enc, float* __restrict__ hid, float* __restrict__ xh0)
{
    const int b   = blockIdx.x >> 1;
    const int dir = blockIdx.x & 1;
    const float* gpre = dir ? gpre_b : gpre_f;
    const float* WT   = dir ? WhhT_b : WhhT_f;
    const int len = x_lens[b];
    __shared__ float h_lds[H2_];
    __shared__ float g_lds[G2_];
    const int tid = threadIdx.x;
    float c = 0.f;
    if (tid < H2_) h_lds[tid] = 0.f;
    __syncthreads();

    for (int t = 0; t < S_; t++) {
        bool valid = t < len;
        if (valid) {
            int s_in = dir ? (len - 1 - t) : t;
            float acc = gpre[(long)(b * S_ + s_in) * G2_ + tid];
            #pragma unroll 8
            for (int k = 0; k < H2_; k++)
                acc += h_lds[k] * WT[k * G2_ + tid];
            g_lds[tid] = acc;
            __syncthreads();
            if (tid < H2_) {
                float gi = g_lds[tid], gf = g_lds[H2_ + tid];
                float gg = g_lds[2 * H2_ + tid], go = g_lds[3 * H2_ + tid];
                c = sigf(gf) * c + sigf(gi) * tanh_fast(gg);
                float hn = sigf(go) * tanh_fast(c);
                h_lds[tid] = hn;
                enc[(long)(b * S_ + s_in) * E_ + dir * H2_ + tid] = hn;
            }
            __syncthreads();
        } else {
            if (tid < H2_)
                enc[(long)(b * S_ + t) * E_ + dir * H2_ + tid] = 0.f;
        }
    }
    if (tid < H2_) {
        hid[b * 1024 + dir * H2_ + tid]       = h_lds[tid]; // h
        hid[b * 1024 + 512 + dir * H2_ + tid] = c;          // c
        xh0[b * 1024 + 512 + dir * H2_ + tid] = h_lds[tid]; // h for gates step 0
    }
}

// ---------------------------------------------------------------------------
// Fence-free two-level grid barrier (monotonic counters).
// All cross-WG data uses sc1 (agent-scope) accesses, so no wbl2/inv is
// needed: release = s_waitcnt vmcnt(0) before the arrival atomic (sc1
// stores ack at the coherence point); acquire = nothing (sc1 loads read
// the coherence point directly). L2 stays warm for read-only data.
// ---------------------------------------------------------------------------
__device__ __forceinline__ void grid_bar(unsigned* bar, int w, int tid)
{
    __syncthreads();   // also drains each wave's outstanding stores (vmcnt)
    if (tid == 0) {
        asm volatile("s_waitcnt vmcnt(0)" ::: "memory");
        unsigned a = __hip_atomic_fetch_add(&bar[16 * (w & 7)], 1u,
                        __ATOMIC_RELAXED, __HIP_MEMORY_SCOPE_AGENT);
        unsigned target = (a >> 5) + 1u;      // barrier instance this completes
        if ((a & 31u) == 31u) {               // last of 32 in this sub-group
            unsigned m = __hip_atomic_fetch_add(&bar[128], 1u,
                            __ATOMIC_RELAXED, __HIP_MEMORY_SCOPE_AGENT);
            if ((m & 7u) == 7u)               // last sub-group overall
                __hip_atomic_store(&bar[144], (m >> 3) + 1u,
                                   __ATOMIC_RELAXED, __HIP_MEMORY_SCOPE_AGENT);
        }
        while (__hip_atomic_load(&bar[144], __ATOMIC_RELAXED,
                                 __HIP_MEMORY_SCOPE_AGENT) < target)
            __builtin_amdgcn_s_sleep(8);
        asm volatile("" ::: "memory");
    }
    __syncthreads();
}

// ---------------------------------------------------------------------------
// Fused persistent decoder. 256 WGs x 256 threads, 3 barriers/step.
//  alpha (all WGs): attq = hid @ W_h.T + b_attn  (W_h slice LDS-resident)
//  B     (WGs 0..31, per-batch): scores -> softmax -> ctx (L2-warm enc/encp)
//         then xi = relu(embW + ctx @ Wc2.T) with Wc2 from warm L2.
//  delta (all WGs): gates = [xi|h] @ Wd.T + b_d -> LSTM update (Wd in LDS)
// Cross-WG buffers (hid, attq, xh) accessed sc1 only.
// ---------------------------------------------------------------------------
__global__ __launch_bounds__(256, 1)
void k_decoder(const float* __restrict__ enc, const float* __restrict__ encp,
               const float* __restrict__ embW,
               const float* __restrict__ W_attn, const float* __restrict__ b_attn,
               const float* __restrict__ v_attn, const float* __restrict__ W_comb,
               const float* __restrict__ Wih_d, const float* __restrict__ Whh_d,
               const float* __restrict__ b_d,
               const int* __restrict__ x_lens,
               float* __restrict__ hid, float* __restrict__ xh0,
               float* __restrict__ xh1, float* __restrict__ attq,
               float* __restrict__ Hall, unsigned* __restrict__ bar)
{
    const int w = blockIdx.x;
    const int tid = threadIdx.x;

    __shared__ float WdL[8 * 1028];              // 32896 B: 8 gate rows (K=1024)
    __shared__ float WhL[4 * 1032];              // 16512 B: 4 W_h rows (K=1024)
    __shared__ __align__(16) float red[256];     //  1024 B
    __shared__ __align__(16) float bsc[832];     //  3328 B: B-phase scratch
    __shared__ float g_l[8 * 33];                //  1056 B
    // total = 54816 B

    // ---- stage weights once ----
    for (int i = tid; i < 8 * 1024; i += 256) {
        int lr = i >> 10, k = i & 1023;
        int row = 512 * (lr & 3) + 2 * w + (lr >> 2);
        WdL[lr * 1028 + k] = (k < 512) ? Wih_d[row * 512 + k]
                                       : Whh_d[row * 512 + (k - 512)];
    }
    for (int i = tid; i < 4 * 1024; i += 256) {
        int lr = i >> 10, k = i & 1023;
        WhL[lr * 1032 + k] = W_attn[(long)(4 * (w >> 1) + lr) * 1536 + k];
    }
    __syncthreads();

    const int o  = tid >> 2;            // 0..63 output slot (alpha)
    const int ks = tid & 3;             // K-quarter
    const int bl = o >> 2, lr = o & 3;
    const int ab = 16 * (w & 1) + bl;   // batch for alpha
    const int r8 = tid & 7, b8 = tid >> 3;  // delta mapping

    for (int t = 0; t < T_; t++) {
        float* xh_cur  = (t & 1) ? xh1 : xh0;
        float* xh_next = (t & 1) ? xh0 : xh1;

        // ---- alpha: attq[b][n] = b_attn[n] + hid[b] . W_h[n]
        {
            const float* hr = hid + ab * 1024;
            const float* wr = WhL + lr * 1032;
            float acc = 0.f;
            #pragma unroll 8
            for (int i = 0; i < 64; i++) {
                int k = 16 * i + 4 * ks;
                float2 a0 = ld2(hr + k), a1 = ld2(hr + k + 2);
                float4 v = *(const float4*)(wr + k);
                acc += a0.x * v.x + a0.y * v.y + a1.x * v.z + a1.y * v.w;
            }
            red[tid] = acc;
            __syncthreads();
            if (tid < 64) {
                int b2 = 16 * (w & 1) + (tid >> 2);
                int n2 = 4 * (w >> 1) + (tid & 3);
                float s = red[tid * 4] + red[tid * 4 + 1]
                        + red[tid * 4 + 2] + red[tid * 4 + 3];
                st1(&attq[b2 * 512 + n2], s + b_attn[n2]);
            }
        }
        grid_bar(bar, w, tid);

        // ---- B: scores / softmax / ctx / xi  (WGs 0..31, b = w)
        if (w < 32) {
            float* aq   = bsc;         // 512 (dead after score loop)
            float* part = bsc + 512;   // 64*4
            float* p    = bsc + 768;   // 64
            aq[tid]       = ld1(&attq[w * 512 + tid]);
            aq[tid + 256] = ld1(&attq[w * 512 + 256 + tid]);
            __syncthreads();
            {
                int s = tid >> 2, q = tid & 3;
                const float* ep = encp + (long)(w * S_ + s) * 512;
                float acc = 0.f;
                #pragma unroll 4
                for (int i = 0; i < 128; i++) {
                    int e = q + 4 * i;
                    acc += v_attn[e] * tanh_fast(ep[e] + aq[e]);
                }
                part[s * 4 + q] = acc;
            }
            __syncthreads();
            if (tid < 64) {
                float sc = part[tid * 4] + part[tid * 4 + 1]
                         + part[tid * 4 + 2] + part[tid * 4 + 3];
                if (tid >= x_lens[w]) sc = -1e9f;
                float m = sc;
                for (int off = 32; off; off >>= 1) m = fmaxf(m, __shfl_xor(m, off));
                float e = __expf(sc - m);
                float sum = e;
                for (int off = 32; off; off >>= 1) sum += __shfl_xor(sum, off);
                p[tid] = e / sum;
            }
            __syncthreads();
            float c0 = 0.f, c1 = 0.f;
            for (int s2 = 0; s2 < S_; s2++) {
                float pp = p[s2];
                const float* er = enc + (long)(w * S_ + s2) * 512;
                c0 += pp * er[tid];
                c1 += pp * er[tid + 256];
            }
            // stage ctx into LDS (aq region is dead now)
            bsc[tid]       = c0;
            bsc[tid + 256] = c1;
            __syncthreads();
            // gamma merged: xi[n] = relu(embW + ctx . Wc2[n]), n = tid, tid+256
            const float* wr0 = W_comb + (long)tid * 1024 + 512;
            const float* wr1 = W_comb + ((long)tid + 256) * 1024 + 512;
            float acc0 = 0.f, acc1 = 0.f;
            #pragma unroll 4
            for (int k = 0; k < 512; k += 4) {
                float4 cv  = *(const float4*)&bsc[k];
                float4 w0v = *(const float4*)(wr0 + k);
                float4 w1v = *(const float4*)(wr1 + k);
                acc0 += cv.x * w0v.x + cv.y * w0v.y + cv.z * w0v.z + cv.w * w0v.w;
                acc1 += cv.x * w1v.x + cv.y * w1v.y + cv.z * w1v.z + cv.w * w1v.w;
            }
            float x0 = fmaxf(acc0 + embW[((long)t * 32 + w) * 512 + tid], 0.f);
            float x1 = fmaxf(acc1 + embW[((long)t * 32 + w) * 512 + 256 + tid], 0.f);
            st1(&xh_cur[w * 1024 + tid], x0);
            st1(&xh_cur[w * 1024 + 256 + tid], x1);
        }
        grid_bar(bar, w, tid);

        // ---- delta: gates + LSTM state update (8 gate rows x 32 batches)
        {
            const float* ar = xh_cur + b8 * 1024;
            const float* wl = WdL + r8 * 1028;
            float acc = 0.f;
            #pragma unroll 8
            for (int q = 0; q < 256; q++) {
                float2 a0 = ld2(ar + 4 * q), a1 = ld2(ar + 4 * q + 2);
                float4 v = *(const float4*)(wl + 4 * q);
                acc += a0.x * v.x + a0.y * v.y + a1.x * v.z + a1.y * v.w;
            }
            int row = 512 * (r8 & 3) + 2 * w + (r8 >> 2);
            g_l[r8 * 33 + b8] = acc + b_d[row];
            __syncthreads();
            if (tid < 64) {
                int bb = tid & 31, hl = tid >> 5;
                int hu = 2 * w + hl;
                float gi = g_l[(hl * 4 + 0) * 33 + bb];
                float gf = g_l[(hl * 4 + 1) * 33 + bb];
                float gg = g_l[(hl * 4 + 2) * 33 + bb];
                float go = g_l[(hl * 4 + 3) * 33 + bb];
                float c_old = ld1(&hid[bb * 1024 + 512 + hu]);
                float c_new = sigf(gf) * c_old + sigf(gi) * tanh_fast(gg);
                float h_new = sigf(go) * tanh_fast(c_new);
                st1(&hid[bb * 1024 + hu], h_new);
                st1(&hid[bb * 1024 + 512 + hu], c_new);
                st1(&xh_next[bb * 1024 + 512 + hu], h_new);
                Hall[((long)bb * T_ + t) * 512 + hu] = h_new;  // normal store
            }
        }
        grid_bar(bar, w, tid);
    }
}

// ---------------------------------------------------------------------------
// Per-row logsumexp + in-place subtract over V=32000 logits (one WG per row).
// ---------------------------------------------------------------------------
__global__ __launch_bounds__(256)
void k_lsesub(float* __restrict__ Cl)
{
    const int r = blockIdx.x;
    float* row = Cl + (long)r * V_;
    const int tid = threadIdx.x;
    __shared__ float red[4];
    float m = -1e30f;
    for (int i = tid; i < V_; i += 256) m = fmaxf(m, row[i]);
    for (int off = 32; off; off >>= 1) m = fmaxf(m, __shfl_xor(m, off));
    int w = tid >> 6;
    if ((tid & 63) == 0) red[w] = m;
    __syncthreads();
    m = fmaxf(fmaxf(red[0], red[1]), fmaxf(red[2], red[3]));
    __syncthreads();
    float s = 0.f;
    for (int i = tid; i < V_; i += 256) s += __expf(row[i] - m);
    for (int off = 32; off; off >>= 1) s += __shfl_xor(s, off);
    if ((tid & 63) == 0) red[w] = s;
    __syncthreads();
    s = red[0] + red[1] + red[2] + red[3];
    float l = m + __logf(s);
    float4* r4 = (float4*)row;
    for (int i = tid; i < V_ / 4; i += 256) {
        float4 v = r4[i];
        v.x -= l; v.y -= l; v.z -= l; v.w -= l;
        r4[i] = v;
    }
}

// ---------------------------------------------------------------------------
extern "C" void kernel_launch(void* const* d_in, const int* in_sizes, int n_in,
                              void* d_out, int out_size, void* d_ws, size_t ws_size,
                              hipStream_t stream)
{
    const int*   xs     = (const int*)  d_in[0];
    const int*   x_lens = (const int*)  d_in[1];
    const int*   ys     = (const int*)  d_in[2];
    const float* src_emb= (const float*)d_in[3];
    const float* W_tr   = (const float*)d_in[4];
    const float* b_tr   = (const float*)d_in[5];
    const float* Wih_f  = (const float*)d_in[6];
    const float* Whh_f  = (const float*)d_in[7];
    const float* b_f    = (const float*)d_in[8];
    const float* Wih_b  = (const float*)d_in[9];
    const float* Whh_b  = (const float*)d_in[10];
    const float* b_b    = (const float*)d_in[11];
    const float* W_attn = (const float*)d_in[12];
    const float* b_attn = (const float*)d_in[13];
    const float* v_attn = (const float*)d_in[14];
    const float* tgt_emb= (const float*)d_in[15];
    const float* W_comb = (const float*)d_in[16];
    const float* b_comb = (const float*)d_in[17];
    const float* Wih_d  = (const float*)d_in[18];
    const float* Whh_d  = (const float*)d_in[19];
    const float* b_d    = (const float*)d_in[20];
    const float* W_out  = (const float*)d_in[21];
    const float* b_out  = (const float*)d_in[22];
    float* out = (float*)d_out;

    float* ws = (float*)d_ws;
    size_t off = 0;
    auto alloc = [&](size_t n) { float* p = ws + off; off += n; return p; };
    float* x      = alloc(2048 * 512);
    float* gpre_f = alloc(2048 * 1024);
    float* gpre_b = alloc(2048 * 1024);
    float* enc    = alloc(2048 * 512);
    float* encp   = alloc(2048 * 512);
    float* embW   = alloc(2048 * 512);
    float* Hall   = alloc(2048 * 512);
    float* hid    = alloc(32 * 1024);
    float* xh0    = alloc(32 * 1024);
    float* xh1    = alloc(32 * 1024);
    float* attq   = alloc(32 * 512);
    float* WhhTf  = alloc(256 * 1024);
    float* WhhTb  = alloc(256 * 1024);
    int*   tokens = (int*)alloc(2048);
    unsigned* bar = (unsigned*)alloc(160);
    (void)ws_size; (void)n_in; (void)in_sizes; (void)out_size;

    // prep (also zeroes the grid-barrier state each launch/replay)
    k_prep<<<512, 256, 0, stream>>>(ys, Whh_f, Whh_b, WhhTf, WhhTb, tokens, bar);

    // x = src_emb[xs] @ W_tr.T + b_tr   (M=2048, N=512, K=768)
    gemm_f32<<<dim3(512 / 64, 2048 / 64), 256, 0, stream>>>(src_emb, xs, P_, W_tr, P_, 0, b_tr, x, 512, P_);
    // gpre_f/b = x @ Wih.T + b          (M=2048, N=1024, K=512)
    gemm_f32<<<dim3(1024 / 64, 2048 / 64), 256, 0, stream>>>(x, nullptr, 512, Wih_f, 512, 0, b_f, gpre_f, 1024, 512);
    gemm_f32<<<dim3(1024 / 64, 2048 / 64), 256, 0, stream>>>(x, nullptr, 512, Wih_b, 512, 0, b_b, gpre_b, 1024, 512);

    // encoder recurrence
    k_encoder<<<64, 1024, 0, stream>>>(gpre_f, gpre_b, WhhTf, WhhTb, x_lens, enc, hid, xh0);

    // enc_proj = enc @ W_e.T            (W_attn cols 1024:1536, no bias)
    gemm_f32<<<dim3(512 / 64, 2048 / 64), 256, 0, stream>>>(enc, nullptr, 512, W_attn, 1536, 1024, nullptr, encp, 512, 512);
    // embW = tgt_emb[tokens] @ W_comb[:, :512].T + b_comb   (rows = t*32+b)
    gemm_f32<<<dim3(512 / 64, 2048 / 64), 256, 0, stream>>>(tgt_emb, tokens, 512, W_comb, 1024, 0, b_comb, embW, 512, 512);

    // fused persistent decoder (all 64 steps, cooperative launch,
    // fence-free sc1 barriers, LDS-resident Wd/W_h, 3 barriers/step)
    {
        void* args[] = { (void*)&enc, (void*)&encp, (void*)&embW, (void*)&W_attn,
                         (void*)&b_attn, (void*)&v_attn, (void*)&W_comb,
                         (void*)&Wih_d, (void*)&Whh_d, (void*)&b_d, (void*)&x_lens,
                         (void*)&hid, (void*)&xh0, (void*)&xh1, (void*)&attq,
                         (void*)&Hall, (void*)&bar };
        hipLaunchCooperativeKernel((void*)k_decoder, dim3(NWG), dim3(256), args, 0, stream);
    }

    // logits = Hall @ W_out.T + b_out  -> d_out   (M=2048, N=32000, K=512)
    gemm_f32<<<dim3(V_ / 64, 2048 / 64), 256, 0, stream>>>(Hall, nullptr, 512, W_out, 512, 0, b_out, out, V_, 512);
    // log_softmax (fused lse + subtract)
    k_lsesub<<<2048, 256, 0, stream>>>(out);
}

// Round 5
// 8285.514 us; speedup vs baseline: 1.8107x; 1.0006x over previous
//
#include <hip/hip_runtime.h>
#include <math.h>

#define B_  32
#define S_  64
#define T_  64
#define P_  768
#define E_  512
#define H2_ 256
#define G2_ 1024
#define HD_ 512
#define V_  32000
#define NWG 256

__device__ __forceinline__ float sigf(float x) {
    return 1.0f / (1.0f + __expf(-x));
}
__device__ __forceinline__ float tanh_fast(float x) {
    // tanh(x) = 1 - 2/(exp(2x)+1); exact limits at +-inf
    return 1.0f - 2.0f / (__expf(2.0f * x) + 1.0f);
}

// ---------------------------------------------------------------------------
// prep: transpose Whh_f/Whh_b to [k][gate]; tokens; zero grid-barrier state
// ---------------------------------------------------------------------------
__global__ void k_prep(const int* __restrict__ ys,
                       const float* __restrict__ Whh_f, const float* __restrict__ Whh_b,
                       float* __restrict__ WhhT_f, float* __restrict__ WhhT_b,
                       int* __restrict__ tokens, unsigned* __restrict__ bar)
{
    int i = blockIdx.x * blockDim.x + threadIdx.x;
    int n = gridDim.x * blockDim.x;
    for (int idx = i; idx < G2_ * H2_; idx += n) {
        int k = idx / G2_, g = idx % G2_;
        WhhT_f[idx] = Whh_f[g * H2_ + k];
        WhhT_b[idx] = Whh_b[g * H2_ + k];
    }
    for (int idx = i; idx < T_ * B_; idx += n) {
        int t = idx / B_, b = idx % B_;
        tokens[idx] = (t == 0) ? 1 : ys[b * (T_ + 1) + t];
    }
    for (int idx = i; idx < 1024; idx += n) bar[idx] = 0u;
}

// ---------------------------------------------------------------------------
// Tiled fp32 GEMM:  C[m,n] = bias[n] + sum_k A(m)[k] * W[n*ldw + woff + k]
// ---------------------------------------------------------------------------
__global__ __launch_bounds__(256)
void gemm_f32(const float* __restrict__ A, const int* __restrict__ gidx, int lda,
              const float* __restrict__ W, int ldw, int woff,
              const float* __restrict__ bias,
              float* __restrict__ C, int ldc, int K)
{
    __shared__ __align__(16) float As[16][64];
    __shared__ __align__(16) float Bs[16][64];
    const int m0 = blockIdx.y * 64;
    const int n0 = blockIdx.x * 64;
    const int tid = threadIdx.x;
    const int tm = tid & 15, tn = tid >> 4;
    const int la_m = tid >> 2;        // 0..63
    const int la_k = (tid & 3) * 4;   // 0,4,8,12
    float acc[4][4] = {};

    const int am = m0 + la_m;
    const float* arow = A + (long)(gidx ? gidx[am] : am) * lda;
    const float* wrow = W + (long)(n0 + la_m) * ldw + woff;

    for (int k0 = 0; k0 < K; k0 += 16) {
        float4 av = *(const float4*)(arow + k0 + la_k);
        float4 wv = *(const float4*)(wrow + k0 + la_k);
        As[la_k + 0][la_m] = av.x; As[la_k + 1][la_m] = av.y;
        As[la_k + 2][la_m] = av.z; As[la_k + 3][la_m] = av.w;
        Bs[la_k + 0][la_m] = wv.x; Bs[la_k + 1][la_m] = wv.y;
        Bs[la_k + 2][la_m] = wv.z; Bs[la_k + 3][la_m] = wv.w;
        __syncthreads();
        #pragma unroll
        for (int kk = 0; kk < 16; kk++) {
            float4 a = *(const float4*)&As[kk][tm * 4];
            float4 b = *(const float4*)&Bs[kk][tn * 4];
            acc[0][0] += a.x * b.x; acc[0][1] += a.x * b.y; acc[0][2] += a.x * b.z; acc[0][3] += a.x * b.w;
            acc[1][0] += a.y * b.x; acc[1][1] += a.y * b.y; acc[1][2] += a.y * b.z; acc[1][3] += a.y * b.w;
            acc[2][0] += a.z * b.x; acc[2][1] += a.z * b.y; acc[2][2] += a.z * b.z; acc[2][3] += a.z * b.w;
            acc[3][0] += a.w * b.x; acc[3][1] += a.w * b.y; acc[3][2] += a.w * b.z; acc[3][3] += a.w * b.w;
        }
        __syncthreads();
    }
    float b0 = bias ? bias[n0 + tn * 4 + 0] : 0.f;
    float b1 = bias ? bias[n0 + tn * 4 + 1] : 0.f;
    float b2 = bias ? bias[n0 + tn * 4 + 2] : 0.f;
    float b3 = bias ? bias[n0 + tn * 4 + 3] : 0.f;
    #pragma unroll
    for (int i = 0; i < 4; i++) {
        long m = m0 + tm * 4 + i;
        float4 o = make_float4(acc[i][0] + b0, acc[i][1] + b1, acc[i][2] + b2, acc[i][3] + b3);
        *(float4*)&C[m * ldc + n0 + tn * 4] = o;
    }
}

// ---------------------------------------------------------------------------
// BiLSTM encoder recurrence: one WG per (b, dir); 1024 threads (one per gate).
// ---------------------------------------------------------------------------
__global__ __launch_bounds__(1024)
void k_encoder(const float* __restrict__ gpre_f, const float* __restrict__ gpre_b,
               const float* __restrict__ WhhT_f, const float* __restrict__ WhhT_b,
               const int* __restrict__ x_lens,
               float* __restrict__ enc, float* __restrict__ hid)
{
    const int b   = blockIdx.x >> 1;
    const int dir = blockIdx.x & 1;
    const float* gpre = dir ? gpre_b : gpre_f;
    const float* WT   = dir ? WhhT_b : WhhT_f;
    const int len = x_lens[b];
    __shared__ float h_lds[H2_];
    __shared__ float g_lds[G2_];
    const int tid = threadIdx.x;
    float c = 0.f;
    if (tid < H2_) h_lds[tid] = 0.f;
    __syncthreads();

    for (int t = 0; t < S_; t++) {
        bool valid = t < len;
        if (valid) {
            int s_in = dir ? (len - 1 - t) : t;
            float acc = gpre[(long)(b * S_ + s_in) * G2_ + tid];
            #pragma unroll 8
            for (int k = 0; k < H2_; k++)
                acc += h_lds[k] * WT[k * G2_ + tid];
            g_lds[tid] = acc;
            __syncthreads();
            if (tid < H2_) {
                float gi = g_lds[tid], gf = g_lds[H2_ + tid];
                float gg = g_lds[2 * H2_ + tid], go = g_lds[3 * H2_ + tid];
                c = sigf(gf) * c + sigf(gi) * tanh_fast(gg);
                float hn = sigf(go) * tanh_fast(c);
                h_lds[tid] = hn;
                enc[(long)(b * S_ + s_in) * E_ + dir * H2_ + tid] = hn;
            }
            __syncthreads();
        } else {
            if (tid < H2_)
                enc[(long)(b * S_ + t) * E_ + dir * H2_ + tid] = 0.f;
        }
    }
    if (tid < H2_) {
        hid[b * 1024 + dir * H2_ + tid]       = h_lds[tid]; // h
        hid[b * 1024 + 512 + dir * H2_ + tid] = c;          // c
    }
}

// ---------------------------------------------------------------------------
// Store-only two-level grid barrier (no atomic RMW, monotonic generations).
//  bar[w]        w=0..255 : per-WG arrival generation (own word)
//  bar[512+16g]  g=0..7   : leader-group generation
//  bar[768]               : release generation
// Release: __threadfence() (drain + wbl2) before the arrival store.
// Acquire: __threadfence() (inv) after observing the release word.
// Leaders (WGs 0..7) wave-poll their 32 arrival words with __all; WG0
// polls the 8 leader words; everyone polls the release word (s_sleep(1)).
// ---------------------------------------------------------------------------
__device__ __forceinline__ void grid_bar(unsigned* bar, int w, int tid, unsigned gen)
{
    __syncthreads();
    if (tid == 0) {
        __threadfence();   // release: push this WG's stores to IF/L3
        __hip_atomic_store(&bar[w], gen, __ATOMIC_RELAXED, __HIP_MEMORY_SCOPE_AGENT);
    }
    if (w < 8 && tid < 64) {
        bool mine = tid < 32;
        for (;;) {
            unsigned v = mine ? __hip_atomic_load(&bar[32 * w + tid],
                                 __ATOMIC_RELAXED, __HIP_MEMORY_SCOPE_AGENT) : gen;
            if (__all(v >= gen)) break;
            __builtin_amdgcn_s_sleep(1);
        }
        if (tid == 0)
            __hip_atomic_store(&bar[512 + 16 * w], gen,
                               __ATOMIC_RELAXED, __HIP_MEMORY_SCOPE_AGENT);
    }
    if (w == 0 && tid < 64) {
        bool mine = tid < 8;
        for (;;) {
            unsigned v = mine ? __hip_atomic_load(&bar[512 + 16 * tid],
                                 __ATOMIC_RELAXED, __HIP_MEMORY_SCOPE_AGENT) : gen;
            if (__all(v >= gen)) break;
            __builtin_amdgcn_s_sleep(1);
        }
        if (tid == 0)
            __hip_atomic_store(&bar[768], gen,
                               __ATOMIC_RELAXED, __HIP_MEMORY_SCOPE_AGENT);
    }
    if (tid == 0) {
        while (__hip_atomic_load(&bar[768], __ATOMIC_RELAXED,
                                 __HIP_MEMORY_SCOPE_AGENT) < gen)
            __builtin_amdgcn_s_sleep(1);
        __threadfence();   // acquire: invalidate so fresh data is re-fetched
    }
    __syncthreads();
}

// ---------------------------------------------------------------------------
// Fused persistent decoder. 256 WGs x 256 threads, 4 phases/step.
//  A (all WGs): attq rows {2w,2w+1} = hid @ W_h.T + b_attn  (W_h in LDS),
//               PLUS gate h-half partial: g_ph[8][32] = h @ Whh_d.T (Wd in LDS)
//  B (WGs 0..31): scores -> softmax -> ctx (per-batch)
//  C (all WGs): xi rows {2w,2w+1} = relu(embW + ctx @ Wc2.T) (Wc2 from L2)
//  D (all WGs): gates = xi-half + g_ph + b_d -> LSTM update (Wd in LDS)
// All activation loads are plain vectorized float4 (max MLP); coherence
// from the fenced barrier (round-2-proven pattern).
// ---------------------------------------------------------------------------
__global__ __launch_bounds__(256, 1)
void k_decoder(const float* __restrict__ enc, const float* __restrict__ encp,
               const float* __restrict__ embW,
               const float* __restrict__ W_attn, const float* __restrict__ b_attn,
               const float* __restrict__ v_attn, const float* __restrict__ W_comb,
               const float* __restrict__ Wih_d, const float* __restrict__ Whh_d,
               const float* __restrict__ b_d,
               const int* __restrict__ x_lens,
               float* __restrict__ hid, float* __restrict__ xi,
               float* __restrict__ attq, float* __restrict__ ctxg,
               float* __restrict__ Hall, unsigned* __restrict__ bar)
{
    const int w = blockIdx.x;
    const int tid = threadIdx.x;

    __shared__ float WdL[8 * 1028];              // 32896 B: 8 gate rows (K=1024)
    __shared__ float WhL[2 * 1028];              //  8224 B: 2 W_h rows (K=1024)
    __shared__ __align__(16) float red[256];     //  1024 B
    __shared__ __align__(16) float bsc[832];     //  3328 B: B-phase scratch
    __shared__ float g_l[8 * 33];                //  1056 B: final gates
    __shared__ float g_ph[8 * 33];               //  1056 B: h-half gate partials
    // total = 47584 B

    // ---- stage weights once ----
    for (int i = tid; i < 8 * 1024; i += 256) {
        int lr = i >> 10, k = i & 1023;
        int row = 512 * (lr & 3) + 2 * w + (lr >> 2);
        WdL[lr * 1028 + k] = (k < 512) ? Wih_d[row * 512 + k]
                                       : Whh_d[row * 512 + (k - 512)];
    }
    for (int i = tid; i < 2 * 1024; i += 256) {
        int lr = i >> 10, k = i & 1023;
        WhL[lr * 1028 + k] = W_attn[(long)(2 * w + lr) * 1536 + k];
    }
    __syncthreads();

    const int bA = tid & 31;            // batch (phases A/C)
    const int rA = (tid >> 5) & 1;      // row-in-pair
    const int ksA = tid >> 6;           // K-quarter
    const int r8 = tid & 7, b8 = tid >> 3;  // phases A(gh)/D mapping
    unsigned gen = 1;

    for (int t = 0; t < T_; t++) {
        // ---- phase A: attq + gate h-half partial
        {
            const float* hq = hid + (long)bA * 1024 + ksA * 256;
            const float* wr = WhL + rA * 1028 + ksA * 256;
            float acc = 0.f;
            #pragma unroll 8
            for (int i = 0; i < 64; i++) {
                float4 a = *(const float4*)(hq + 4 * i);
                float4 v = *(const float4*)(wr + 4 * i);
                acc += a.x * v.x + a.y * v.y + a.z * v.z + a.w * v.w;
            }
            red[tid] = acc;
            __syncthreads();
            if (tid < 64) {
                int b2 = tid & 31, r2 = tid >> 5;
                float s = red[tid] + red[tid + 64] + red[tid + 128] + red[tid + 192];
                attq[b2 * 512 + 2 * w + r2] = s + b_attn[2 * w + r2];
            }
            // gate h-half: g_ph[r8][b8] = hid_h[b8] . Whh_d[row]
            const float* hr = hid + (long)b8 * 1024;       // h = hid[:, :512]
            const float* wl = WdL + r8 * 1028 + 512;
            float acch = 0.f;
            #pragma unroll 8
            for (int q = 0; q < 128; q++) {
                float4 a = *(const float4*)(hr + 4 * q);
                float4 v = *(const float4*)(wl + 4 * q);
                acch += a.x * v.x + a.y * v.y + a.z * v.z + a.w * v.w;
            }
            g_ph[r8 * 33 + b8] = acch;
        }
        grid_bar(bar, w, tid, gen); gen++;

        // ---- phase B: scores / softmax / ctx  (WGs 0..31, b = w)
        if (w < 32) {
            float* aq   = bsc;         // 512
            float* part = bsc + 512;   // 64*4
            float* p    = bsc + 768;   // 64
            aq[tid]       = attq[w * 512 + tid];
            aq[tid + 256] = attq[w * 512 + 256 + tid];
            __syncthreads();
            {
                int s = tid >> 2, q = tid & 3;
                const float* ep = encp + (long)(w * S_ + s) * 512;
                float acc = 0.f;
                #pragma unroll 4
                for (int i = 0; i < 128; i++) {
                    int e = q + 4 * i;
                    acc += v_attn[e] * tanh_fast(ep[e] + aq[e]);
                }
                part[s * 4 + q] = acc;
            }
            __syncthreads();
            if (tid < 64) {
                float sc = part[tid * 4] + part[tid * 4 + 1]
                         + part[tid * 4 + 2] + part[tid * 4 + 3];
                if (tid >= x_lens[w]) sc = -1e9f;
                float m = sc;
                for (int off = 32; off; off >>= 1) m = fmaxf(m, __shfl_xor(m, off));
                float e = __expf(sc - m);
                float sum = e;
                for (int off = 32; off; off >>= 1) sum += __shfl_xor(sum, off);
                p[tid] = e / sum;
            }
            __syncthreads();
            float c0 = 0.f, c1 = 0.f;
            for (int s2 = 0; s2 < S_; s2++) {
                float pp = p[s2];
                const float* er = enc + (long)(w * S_ + s2) * 512;
                c0 += pp * er[tid];
                c1 += pp * er[tid + 256];
            }
            ctxg[w * 512 + tid]       = c0;
            ctxg[w * 512 + 256 + tid] = c1;
        }
        grid_bar(bar, w, tid, gen); gen++;

        // ---- phase C: xi rows {2w,2w+1} = relu(embW + ctx @ Wc2.T)
        {
            const float* cr = ctxg + (long)bA * 512 + ksA * 128;
            const float* wr = W_comb + (long)(2 * w + rA) * 1024 + 512 + ksA * 128;
            float acc = 0.f;
            #pragma unroll 8
            for (int i = 0; i < 32; i++) {
                float4 a = *(const float4*)(cr + 4 * i);
                float4 v = *(const float4*)(wr + 4 * i);
                acc += a.x * v.x + a.y * v.y + a.z * v.z + a.w * v.w;
            }
            red[tid] = acc;
            __syncthreads();
            if (tid < 64) {
                int b2 = tid & 31, r2 = tid >> 5;
                int n2 = 2 * w + r2;
                float s = red[tid] + red[tid + 64] + red[tid + 128] + red[tid + 192];
                float val = s + embW[((long)t * 32 + b2) * 512 + n2];
                xi[b2 * 512 + n2] = fmaxf(val, 0.f);
            }
        }
        grid_bar(bar, w, tid, gen); gen++;

        // ---- phase D: gates (xi half) + g_ph + LSTM state update
        {
            const float* ar = xi + (long)b8 * 512;
            const float* wl = WdL + r8 * 1028;
            float acc = 0.f;
            #pragma unroll 8
            for (int q = 0; q < 128; q++) {
                float4 a = *(const float4*)(ar + 4 * q);
                float4 v = *(const float4*)(wl + 4 * q);
                acc += a.x * v.x + a.y * v.y + a.z * v.z + a.w * v.w;
            }
            int row = 512 * (r8 & 3) + 2 * w + (r8 >> 2);
            g_l[r8 * 33 + b8] = acc + g_ph[r8 * 33 + b8] + b_d[row];
            __syncthreads();
            if (tid < 64) {
                int bb = tid & 31, hl = tid >> 5;
                int hu = 2 * w + hl;
                float gi = g_l[(hl * 4 + 0) * 33 + bb];
                float gf = g_l[(hl * 4 + 1) * 33 + bb];
                float gg = g_l[(hl * 4 + 2) * 33 + bb];
                float go = g_l[(hl * 4 + 3) * 33 + bb];
                float c_old = hid[bb * 1024 + 512 + hu];
                float c_new = sigf(gf) * c_old + sigf(gi) * tanh_fast(gg);
                float h_new = sigf(go) * tanh_fast(c_new);
                hid[bb * 1024 + hu] = h_new;
                hid[bb * 1024 + 512 + hu] = c_new;
                Hall[((long)bb * T_ + t) * 512 + hu] = h_new;
            }
        }
        grid_bar(bar, w, tid, gen); gen++;
    }
}

// ---------------------------------------------------------------------------
// Per-row logsumexp + in-place subtract over V=32000 logits (one WG per row).
// ---------------------------------------------------------------------------
__global__ __launch_bounds__(256)
void k_lsesub(float* __restrict__ Cl)
{
    const int r = blockIdx.x;
    float* row = Cl + (long)r * V_;
    const int tid = threadIdx.x;
    __shared__ float red[4];
    float m = -1e30f;
    for (int i = tid; i < V_; i += 256) m = fmaxf(m, row[i]);
    for (int off = 32; off; off >>= 1) m = fmaxf(m, __shfl_xor(m, off));
    int w = tid >> 6;
    if ((tid & 63) == 0) red[w] = m;
    __syncthreads();
    m = fmaxf(fmaxf(red[0], red[1]), fmaxf(red[2], red[3]));
    __syncthreads();
    float s = 0.f;
    for (int i = tid; i < V_; i += 256) s += __expf(row[i] - m);
    for (int off = 32; off; off >>= 1) s += __shfl_xor(s, off);
    if ((tid & 63) == 0) red[w] = s;
    __syncthreads();
    s = red[0] + red[1] + red[2] + red[3];
    float l = m + __logf(s);
    float4* r4 = (float4*)row;
    for (int i = tid; i < V_ / 4; i += 256) {
        float4 v = r4[i];
        v.x -= l; v.y -= l; v.z -= l; v.w -= l;
        r4[i] = v;
    }
}

// ---------------------------------------------------------------------------
extern "C" void kernel_launch(void* const* d_in, const int* in_sizes, int n_in,
                              void* d_out, int out_size, void* d_ws, size_t ws_size,
                              hipStream_t stream)
{
    const int*   xs     = (const int*)  d_in[0];
    const int*   x_lens = (const int*)  d_in[1];
    const int*   ys     = (const int*)  d_in[2];
    const float* src_emb= (const float*)d_in[3];
    const float* W_tr   = (const float*)d_in[4];
    const float* b_tr   = (const float*)d_in[5];
    const float* Wih_f  = (const float*)d_in[6];
    const float* Whh_f  = (const float*)d_in[7];
    const float* b_f    = (const float*)d_in[8];
    const float* Wih_b  = (const float*)d_in[9];
    const float* Whh_b  = (const float*)d_in[10];
    const float* b_b    = (const float*)d_in[11];
    const float* W_attn = (const float*)d_in[12];
    const float* b_attn = (const float*)d_in[13];
    const float* v_attn = (const float*)d_in[14];
    const float* tgt_emb= (const float*)d_in[15];
    const float* W_comb = (const float*)d_in[16];
    const float* b_comb = (const float*)d_in[17];
    const float* Wih_d  = (const float*)d_in[18];
    const float* Whh_d  = (const float*)d_in[19];
    const float* b_d    = (const float*)d_in[20];
    const float* W_out  = (const float*)d_in[21];
    const float* b_out  = (const float*)d_in[22];
    float* out = (float*)d_out;

    float* ws = (float*)d_ws;
    size_t off = 0;
    auto alloc = [&](size_t n) { float* p = ws + off; off += n; return p; };
    float* x      = alloc(2048 * 512);
    float* gpre_f = alloc(2048 * 1024);
    float* gpre_b = alloc(2048 * 1024);
    float* enc    = alloc(2048 * 512);
    float* encp   = alloc(2048 * 512);
    float* embW   = alloc(2048 * 512);
    float* Hall   = alloc(2048 * 512);
    float* hid    = alloc(32 * 1024);
    float* xi     = alloc(32 * 512);
    float* attq   = alloc(32 * 512);
    float* ctxg   = alloc(32 * 512);
    float* WhhTf  = alloc(256 * 1024);
    float* WhhTb  = alloc(256 * 1024);
    int*   tokens = (int*)alloc(2048);
    unsigned* bar = (unsigned*)alloc(1024);
    (void)ws_size; (void)n_in; (void)in_sizes; (void)out_size;

    // prep (also zeroes the grid-barrier state each launch/replay)
    k_prep<<<512, 256, 0, stream>>>(ys, Whh_f, Whh_b, WhhTf, WhhTb, tokens, bar);

    // x = src_emb[xs] @ W_tr.T + b_tr   (M=2048, N=512, K=768)
    gemm_f32<<<dim3(512 / 64, 2048 / 64), 256, 0, stream>>>(src_emb, xs, P_, W_tr, P_, 0, b_tr, x, 512, P_);
    // gpre_f/b = x @ Wih.T + b          (M=2048, N=1024, K=512)
    gemm_f32<<<dim3(1024 / 64, 2048 / 64), 256, 0, stream>>>(x, nullptr, 512, Wih_f, 512, 0, b_f, gpre_f, 1024, 512);
    gemm_f32<<<dim3(1024 / 64, 2048 / 64), 256, 0, stream>>>(x, nullptr, 512, Wih_b, 512, 0, b_b, gpre_b, 1024, 512);

    // encoder recurrence
    k_encoder<<<64, 1024, 0, stream>>>(gpre_f, gpre_b, WhhTf, WhhTb, x_lens, enc, hid);

    // enc_proj = enc @ W_e.T            (W_attn cols 1024:1536, no bias)
    gemm_f32<<<dim3(512 / 64, 2048 / 64), 256, 0, stream>>>(enc, nullptr, 512, W_attn, 1536, 1024, nullptr, encp, 512, 512);
    // embW = tgt_emb[tokens] @ W_comb[:, :512].T + b_comb   (rows = t*32+b)
    gemm_f32<<<dim3(512 / 64, 2048 / 64), 256, 0, stream>>>(tgt_emb, tokens, 512, W_comb, 1024, 0, b_comb, embW, 512, 512);

    // fused persistent decoder (all 64 steps, cooperative launch,
    // store-only fenced barriers, plain vectorized loads, 4 lean phases)
    {
        void* args[] = { (void*)&enc, (void*)&encp, (void*)&embW, (void*)&W_attn,
                         (void*)&b_attn, (void*)&v_attn, (void*)&W_comb,
                         (void*)&Wih_d, (void*)&Whh_d, (void*)&b_d, (void*)&x_lens,
                         (void*)&hid, (void*)&xi, (void*)&attq, (void*)&ctxg,
                         (void*)&Hall, (void*)&bar };
        hipLaunchCooperativeKernel((void*)k_decoder, dim3(NWG), dim3(256), args, 0, stream);
    }

    // logits = Hall @ W_out.T + b_out  -> d_out   (M=2048, N=32000, K=512)
    gemm_f32<<<dim3(V_ / 64, 2048 / 64), 256, 0, stream>>>(Hall, nullptr, 512, W_out, 512, 0, b_out, out, V_, 512);
    // log_softmax (fused lse + subtract)
    k_lsesub<<<2048, 256, 0, stream>>>(out);
}